// Round 2
// baseline (149.380 us; speedup 1.0000x reference)
//
#include <hip/hip_runtime.h>
#include <stdint.h>

// Problem constants (B,C,D,H,W) = (2,1,128,256,256)
#define BB 2
#define DD 128
#define HH 256
#define WW 256
static constexpr int64_t N = (int64_t)BB * DD * HH * WW;   // 16,777,216
static constexpr int WPR    = WW / 64;                     // 4 words per row
static constexpr int NWORDS = BB * DD * HH * WPR;          // 262,144 words (2 MB)
static constexpr int NROWS  = BB * DD * HH;                // 65,536 rows
static constexpr int K1_BLOCKS = NROWS / 8;                // 8192 (4 waves x 2 rows)
static constexpr int K2_BLOCKS = (HH / 16) * (DD / 16) * (BB * WPR); // 1024

// ---------------------------------------------------------------------------
// K1: fused predicate + X-dilation + base L1 sum, via wave64 __ballot.
// Lane l holds float4 = voxels 4l..4l+3 of a row. Ballot of component c
// gives word Bc with bit l = voxel 4l+c (interleaved layout). X-dilation
// (radius 3) is then pure uniform 64-bit SALU on B0..B3 — no cross-lane
// shuffles at all on the mask path. Each wave processes 2 rows for MLP.
// The stored mask layout is: word c of a row has bit l = voxel 4l+c.
// K2's OR-dilation is bitwise and layout-agnostic; only its residual
// fetch path needs the bit->voxel map.
// ---------------------------------------------------------------------------
__global__ __launch_bounds__(256) void mask_xdil_sum(const float* __restrict__ tgt,
                                                     const float* __restrict__ inp,
                                                     uint64_t* __restrict__ mask,
                                                     double* __restrict__ p0) {
    const int wave = threadIdx.x >> 6;
    const int lane = threadIdx.x & 63;
    float s = 0.0f;

    #pragma unroll
    for (int r = 0; r < 2; ++r) {
        const int row = blockIdx.x * 8 + wave * 2 + r;
        const int64_t base = (int64_t)row * WW;
        const float4 t = ((const float4*)(tgt + base))[lane];
        const float4 a = ((const float4*)(inp + base))[lane];

        s += fabsf(t.x - a.x) + fabsf(t.y - a.y)
           + fabsf(t.z - a.z) + fabsf(t.w - a.w);

        const uint64_t b0 = __ballot(t.x > 0.0f && t.x < 1.0f);
        const uint64_t b1 = __ballot(t.y > 0.0f && t.y < 1.0f);
        const uint64_t b2 = __ballot(t.z > 0.0f && t.z < 1.0f);
        const uint64_t b3 = __ballot(t.w > 0.0f && t.w < 1.0f);

        const uint64_t U  = b0 | b1 | b2 | b3;
        const uint64_t d0 = U | ((b1 | b2 | b3) << 1);
        const uint64_t d1 = U | ((b2 | b3) << 1) | (b0 >> 1);
        const uint64_t d2 = U | (b3 << 1) | ((b0 | b1) >> 1);
        const uint64_t d3 = U | ((b0 | b1 | b2) >> 1);

        // lanes 0..3 store the row's 4 words (one 32B coalesced store)
        const uint64_t dv = (lane & 2) ? ((lane & 1) ? d3 : d2)
                                       : ((lane & 1) ? d1 : d0);
        if (lane < 4)
            mask[(int64_t)row * WPR + lane] = dv;
    }

    // wave reduce -> block partial (only cross-lane traffic in the kernel)
    #pragma unroll
    for (int off = 32; off > 0; off >>= 1)
        s += __shfl_down(s, off, 64);
    __shared__ float wsum[4];
    if (lane == 0) wsum[wave] = s;
    __syncthreads();
    if (threadIdx.x == 0)
        p0[blockIdx.x] = (double)((wsum[0] + wsum[1]) + (wsum[2] + wsum[3]));
}

// ---------------------------------------------------------------------------
// K2: fused Y+Z dilation (radius 3 each) + residual reduction.
// Block = 16x16 (y,z) words for fixed (b,wx). Raw 22x22 halo tile ->
// y-dilate -> z-dilate into register word v. loss*N = 11*S0 - 10*SA where
// SA = sum_{dilated==0} |t-i|. If v == all-ones (overwhelmingly common)
// a thread contributes nothing and issues ZERO data loads; otherwise it
// fetches only the voxels of the zero bits (voxel = 4*bit + wx in the
// interleaved layout). The dilated mask is never written to memory.
// ---------------------------------------------------------------------------
__global__ __launch_bounds__(256) void yz_dil_reduce(const uint64_t* __restrict__ in,
                                                     const float* __restrict__ inp,
                                                     const float* __restrict__ tgt,
                                                     double* __restrict__ p1) {
    __shared__ uint64_t raw[22][23];   // +1 pad
    __shared__ uint64_t yd[22][17];    // +1 pad
    const int ty = threadIdx.x & 15;
    const int tz = threadIdx.x >> 4;
    const int y0 = blockIdx.x * 16;
    const int z0 = blockIdx.y * 16;
    const int b  = blockIdx.z >> 2;
    const int wx = blockIdx.z & 3;

    for (int idx = threadIdx.x; idx < 22 * 22; idx += 256) {
        const int zz = idx / 22, yy = idx % 22;
        const int gz = z0 - 3 + zz, gy = y0 - 3 + yy;
        uint64_t v = 0;
        if (gz >= 0 && gz < DD && gy >= 0 && gy < HH)
            v = in[(((int64_t)(b * DD + gz)) * HH + gy) * WPR + wx];
        raw[zz][yy] = v;
    }
    __syncthreads();

    for (int idx = threadIdx.x; idx < 22 * 16; idx += 256) {
        const int zz = idx >> 4, yy = idx & 15;
        uint64_t v = 0;
        #pragma unroll
        for (int d = 0; d < 7; d++) v |= raw[zz][yy + d];
        yd[zz][yy] = v;
    }
    __syncthreads();

    uint64_t v = 0;
    #pragma unroll
    for (int d = 0; d < 7; d++) v |= yd[tz + d][ty];

    // residual: |t-i| at voxels whose dilated mask bit is 0
    float sab = 0.0f;
    if (v != ~0ull) {
        uint64_t z = ~v;
        const int64_t vox = (((int64_t)(b * DD + z0 + tz)) * HH + y0 + ty) * WW + wx;
        while (z) {
            const int l = __ffsll((unsigned long long)z) - 1;
            z &= z - 1;
            const int64_t o = vox + 4 * (int64_t)l;   // voxel = 4*bit + wx
            sab += fabsf(tgt[o] - inp[o]);
        }
    }

    #pragma unroll
    for (int off = 32; off > 0; off >>= 1)
        sab += __shfl_down(sab, off, 64);
    __shared__ float ws[4];
    const int lane = threadIdx.x & 63;
    const int wv   = threadIdx.x >> 6;
    if (lane == 0) ws[wv] = sab;
    __syncthreads();
    if (threadIdx.x == 0) {
        const int flat = blockIdx.x + gridDim.x * (blockIdx.y + gridDim.y * blockIdx.z);
        p1[flat] = (double)((ws[0] + ws[1]) + (ws[2] + ws[3]));
    }
}

// ---------------------------------------------------------------------------
// K3: sum partials; out = (11*S0 - 10*SA) / N.
// ---------------------------------------------------------------------------
__global__ __launch_bounds__(1024) void finalize(const double* __restrict__ p0,
                                                 const double* __restrict__ p1,
                                                 float* __restrict__ out) {
    double s0 = 0.0, sa = 0.0;
    for (int i = threadIdx.x; i < K1_BLOCKS; i += 1024) s0 += p0[i];
    for (int i = threadIdx.x; i < K2_BLOCKS; i += 1024) sa += p1[i];
    #pragma unroll
    for (int off = 32; off > 0; off >>= 1) {
        s0 += __shfl_down(s0, off, 64);
        sa += __shfl_down(sa, off, 64);
    }
    __shared__ double w0[16], wa[16];
    const int lane = threadIdx.x & 63;
    const int wv   = threadIdx.x >> 6;
    if (lane == 0) { w0[wv] = s0; wa[wv] = sa; }
    __syncthreads();
    if (threadIdx.x == 0) {
        double S0 = 0.0, SA = 0.0;
        #pragma unroll
        for (int k = 0; k < 16; k++) { S0 += w0[k]; SA += wa[k]; }
        out[0] = (float)((11.0 * S0 - 10.0 * SA) / (double)N);
    }
}

extern "C" void kernel_launch(void* const* d_in, const int* in_sizes, int n_in,
                              void* d_out, int out_size, void* d_ws, size_t ws_size,
                              hipStream_t stream) {
    const float* inp = (const float*)d_in[0];   // "input"
    const float* tgt = (const float*)d_in[1];   // "target"
    float* out = (float*)d_out;

    // workspace layout (every region fully written each run; no poison reads)
    double*   p0    = (double*)d_ws;                           // 8192 doubles = 64 KB
    double*   p1    = (double*)((char*)d_ws + 96 * 1024);      // 1024 doubles = 8 KB
    uint64_t* mask0 = (uint64_t*)((char*)d_ws + 256 * 1024);   // 2 MB

    mask_xdil_sum<<<K1_BLOCKS, 256, 0, stream>>>(tgt, inp, mask0, p0);
    yz_dil_reduce<<<dim3(HH / 16, DD / 16, BB * WPR), 256, 0, stream>>>(mask0, inp, tgt, p1);
    finalize<<<1, 1024, 0, stream>>>(p0, p1, out);
}